// Round 1
// baseline (4948.199 us; speedup 1.0000x reference)
//
#include <hip/hip_runtime.h>
#include <hip/hip_bf16.h>
#include <math.h>

#define HW   36864        // 192*192
#define BHW  73728        // 2*HW
#define NB   2
#define NC   128

// ---------------------------------------------------------------- rmsnorm
__global__ __launch_bounds__(256)
void rmsnorm_kernel(const float* __restrict__ x, const float* __restrict__ s,
                    const float* __restrict__ bi, float* __restrict__ y)
{
    int P = blockIdx.x * 256 + threadIdx.x;          // 0..BHW-1
    int b = P / HW; int pp = P - b * HW;
    const float* xb = x + (size_t)b * NC * HW + pp;
    float ss = 0.f;
#pragma unroll 4
    for (int c = 0; c < NC; ++c) { float v = xb[(size_t)c * HW]; ss = fmaf(v, v, ss); }
    float inv = 1.0f / sqrtf(ss * (1.0f / 128.0f) + 1e-6f);
    float* yb = y + (size_t)b * NC * HW + pp;
#pragma unroll 4
    for (int c = 0; c < NC; ++c)
        yb[(size_t)c * HW] = fmaf(s[c] * xb[(size_t)c * HW], inv, bi[c]);
}

// ---------------------------------------------------------------- conv1x1 (GEMM)
// input fp32 (B,CIN,HW); weights (Cout,CIN); out fp32 or bf16 (B,Cout,HW).
// 128-pixel tile, CIN staged in LDS in chunks of 128 (64KB). Each thread: 1 pixel,
// 8 output channels per inner iteration (weights are wave-uniform scalar loads).
template<int CIN, bool OBF16>
__global__ __launch_bounds__(128)
void conv1x1_kernel(const float* __restrict__ in, const float* __restrict__ wt,
                    const float* __restrict__ bias, int Cout,
                    float* __restrict__ outf, __hip_bfloat16* __restrict__ outb)
{
    __shared__ float tile[128 * 128];
    constexpr int NCH = CIN / 128;
    int t = threadIdx.x;
    int P = blockIdx.x * 128 + t;
    int b = P / HW; int pp = P - b * HW;

    for (int ch = 0; ch < NCH; ++ch) {
        for (int c = 0; c < 128; ++c)
            tile[c * 128 + t] = in[((size_t)(b * CIN + ch * 128 + c)) * HW + pp];
        __syncthreads();

        for (int o = 0; o < Cout; o += 8) {
            float acc[8];
#pragma unroll
            for (int k = 0; k < 8; ++k) acc[k] = (ch == 0) ? bias[o + k] : 0.0f;
#pragma unroll 4
            for (int c = 0; c < 128; ++c) {
                float a = tile[c * 128 + t];
#pragma unroll
                for (int k = 0; k < 8; ++k)
                    acc[k] = fmaf(wt[(size_t)(o + k) * CIN + ch * 128 + c], a, acc[k]);
            }
#pragma unroll
            for (int k = 0; k < 8; ++k) {
                size_t oi = ((size_t)(b * Cout + o + k)) * HW + pp;
                if constexpr (OBF16) {
                    outb[oi] = __float2bfloat16(acc[k]);
                } else {
                    if (ch == 0) outf[oi] = acc[k];
                    else         outf[oi] += acc[k];
                }
            }
        }
        __syncthreads();
    }
}

// ---------------------------------------------------------------- dwconv3x3 + gate
__device__ __forceinline__ float gelu_erf(float v) {
    return v * 0.5f * (1.0f + erff(v * 0.70710678118654752f));
}

__global__ __launch_bounds__(256)
void dwgate_kernel(const __hip_bfloat16* __restrict__ t1, const float* __restrict__ dww,
                   const float* __restrict__ dwb, float* __restrict__ tg)
{
    int o = blockIdx.y;           // 0..255
    int b = blockIdx.z;
    int pp = blockIdx.x * 256 + threadIdx.x;
    int h = pp / 192, w = pp - h * 192;
    const __hip_bfloat16* up = t1 + ((size_t)b * 512 + o) * HW;
    const __hip_bfloat16* vp = t1 + ((size_t)b * 512 + 256 + o) * HW;
    float au = dwb[o], av = dwb[o + 256];
#pragma unroll
    for (int dy = -1; dy <= 1; ++dy) {
        int hh = h + dy; if (hh < 0 || hh >= 192) continue;
#pragma unroll
        for (int dx = -1; dx <= 1; ++dx) {
            int w2 = w + dx; if (w2 < 0 || w2 >= 192) continue;
            float wu = dww[o * 9 + (dy + 1) * 3 + (dx + 1)];
            float wv = dww[(o + 256) * 9 + (dy + 1) * 3 + (dx + 1)];
            int off = hh * 192 + w2;
            au = fmaf(wu, __bfloat162float(up[off]), au);
            av = fmaf(wv, __bfloat162float(vp[off]), av);
        }
    }
    tg[((size_t)b * 256 + o) * HW + pp] = au * gelu_erf(av);
}

// ---------------------------------------------------------------- FFN gate (elementwise)
__global__ __launch_bounds__(256)
void ffngate_kernel(const __hip_bfloat16* __restrict__ t1, float* __restrict__ tg)
{
    size_t i = (size_t)blockIdx.x * 256 + threadIdx.x;     // over B*256*HW
    int b = (int)(i / ((size_t)256 * HW));
    size_t r = i - (size_t)b * 256 * HW;
    int c = (int)(r / HW); int pp = (int)(r - (size_t)c * HW);
    float u = __bfloat162float(t1[((size_t)b * 512 + c) * HW + pp]);
    float v = __bfloat162float(t1[((size_t)b * 512 + 256 + c) * HW + pp]);
    tg[i] = u * gelu_erf(v);
}

// ---------------------------------------------------------------- residual
__global__ __launch_bounds__(256)
void res_set_kernel(float* __restrict__ out, const float* __restrict__ x,
                    const float* __restrict__ t, const float* __restrict__ sc)
{
    size_t i = (size_t)blockIdx.x * 256 + threadIdx.x;
    out[i] = fmaf(sc[0], t[i], x[i]);
}
__global__ __launch_bounds__(256)
void res_add_kernel(float* __restrict__ out, const float* __restrict__ t,
                    const float* __restrict__ sc)
{
    size_t i = (size_t)blockIdx.x * 256 + threadIdx.x;
    out[i] = fmaf(sc[0], t[i], out[i]);
}

// ---------------------------------------------------------------- windowed attention
// One block (64 threads = 1 wave) per (window, head). Roll folded into gather.
__global__ __launch_bounds__(64)
void attn_kernel(const __hip_bfloat16* __restrict__ qkv, const float* __restrict__ rpe,
                 float* __restrict__ attnout)
{
    __shared__ float Ks[32][64];      // [d][j]  — writes lane=j conflict-free, reads broadcast
    __shared__ float Vs[32][64];
    __shared__ float Ss[64][64];      // [j][t]  — lane t owns column t
    __shared__ float rpe_s[225 * 4];

    int lane = threadIdx.x;
    int head = blockIdx.x & 3;
    int widx = blockIdx.x >> 2;
    int wh = widx / 24, ww = widx % 24;
    int b = blockIdx.y;

    for (int i = lane; i < 900; i += 64) rpe_s[i] = rpe[i];

    int ty = lane >> 3, tx = lane & 7;
    int hr = wh * 8 + ty, wr = ww * 8 + tx;          // rolled-frame coords
    int hs = hr + 4; if (hs >= 192) hs -= 192;       // source (and dest) coords
    int wsc = wr + 4; if (wsc >= 192) wsc -= 192;
    int pix = hs * 192 + wsc;

    const __hip_bfloat16* qb = qkv + ((size_t)b * 384 + head * 32) * HW + pix;
    const __hip_bfloat16* kb = qkv + ((size_t)b * 384 + 128 + head * 32) * HW + pix;
    const __hip_bfloat16* vb = qkv + ((size_t)b * 384 + 256 + head * 32) * HW + pix;

    float q[32];
#pragma unroll
    for (int d = 0; d < 32; ++d)
        q[d] = __bfloat162float(qb[(size_t)d * HW]) * 0.17677669529663689f; // /sqrt(32)
#pragma unroll
    for (int d = 0; d < 32; ++d) {
        Ks[d][lane] = __bfloat162float(kb[(size_t)d * HW]);
        Vs[d][lane] = __bfloat162float(vb[(size_t)d * HW]);
    }
    __syncthreads();

    int rt = ((hr < 184) ? 0 : (hr < 188) ? 1 : 2) * 3 +
             ((wr < 184) ? 0 : (wr < 188) ? 1 : 2);
    bool edge = (wh == 23) || (ww == 23);

    for (int j = 0; j < 64; ++j) {
        float acc = 0.f;
#pragma unroll
        for (int d = 0; d < 32; ++d) acc = fmaf(q[d], Ks[d][j], acc);
        int jy = j >> 3, jx = j & 7;
        acc += rpe_s[((ty - jy + 7) * 15 + (tx - jx + 7)) * 4 + head];
        if (edge) {
            int hj = wh * 8 + jy, wj = ww * 8 + jx;
            int rj = ((hj < 184) ? 0 : (hj < 188) ? 1 : 2) * 3 +
                     ((wj < 184) ? 0 : (wj < 188) ? 1 : 2);
            if (rj != rt) acc = -INFINITY;
        }
        Ss[j][lane] = acc;
    }
    // softmax over this lane's row (column t of Ss)
    float m = -INFINITY;
    for (int j = 0; j < 64; ++j) m = fmaxf(m, Ss[j][lane]);
    float l = 0.f;
    for (int j = 0; j < 64; ++j) { float e = __expf(Ss[j][lane] - m); Ss[j][lane] = e; l += e; }
    float inv = 1.0f / l;

    float* ob = attnout + ((size_t)b * 128 + head * 32) * HW + pix;
    for (int d = 0; d < 32; ++d) {
        float acc = 0.f;
        for (int j = 0; j < 64; ++j) acc = fmaf(Ss[j][lane], Vs[d][j], acc);
        ob[(size_t)d * HW] = acc * inv;
    }
}

// ---------------------------------------------------------------- launch
extern "C" void kernel_launch(void* const* d_in, const int* in_sizes, int n_in,
                              void* d_out, int out_size, void* d_ws, size_t ws_size,
                              hipStream_t stream)
{
    const float* x     = (const float*)d_in[0];
    const float* cg_s  = (const float*)d_in[1];
    const float* cg_b  = (const float*)d_in[2];
    const float* pw1_w = (const float*)d_in[3];
    const float* pw1_b = (const float*)d_in[4];
    const float* dw_w  = (const float*)d_in[5];
    const float* dw_b  = (const float*)d_in[6];
    const float* pw2_w = (const float*)d_in[7];
    const float* pw2_b = (const float*)d_in[8];
    const float* beta  = (const float*)d_in[9];
    const float* at_s  = (const float*)d_in[10];
    const float* at_b  = (const float*)d_in[11];
    const float* qkv_w = (const float*)d_in[12];
    const float* qkv_b = (const float*)d_in[13];
    const float* rpe   = (const float*)d_in[14];
    const float* proj_w= (const float*)d_in[15];
    const float* proj_b= (const float*)d_in[16];
    const float* alpha = (const float*)d_in[17];
    const float* ff_s  = (const float*)d_in[18];
    const float* ff_b  = (const float*)d_in[19];
    const float* fc1_w = (const float*)d_in[20];
    const float* fc1_b = (const float*)d_in[21];
    const float* fc2_w = (const float*)d_in[22];
    const float* fc2_b = (const float*)d_in[23];
    const float* gamma = (const float*)d_in[24];
    float* out = (float*)d_out;

    // workspace layout (total 188,743,680 B):
    //   [0, 37.7MB)        t0     fp32 (B,128,HW)  rmsnorm out
    //   [37.7, 113.2MB)    R1:    t1 bf16 (B,512,HW) | qkv bf16 (B,384,HW) | ts fp32 (B,128,HW)
    //   [113.2, 188.7MB)   R2:    tg fp32 (B,256,HW) | attnout fp32 (B,128,HW)
    char* ws = (char*)d_ws;
    float*          t0      = (float*)ws;
    __hip_bfloat16* t1      = (__hip_bfloat16*)(ws + 37748736);
    float*          ts      = (float*)(ws + 37748736);
    __hip_bfloat16* qkvb    = (__hip_bfloat16*)(ws + 37748736);
    float*          tg      = (float*)(ws + 113246208);
    float*          attnout = (float*)(ws + 113246208);

    // ---- stage 1: conv_gated_block
    rmsnorm_kernel<<<288, 256, 0, stream>>>(x, cg_s, cg_b, t0);
    conv1x1_kernel<128, true ><<<576, 128, 0, stream>>>(t0, pw1_w, pw1_b, 512, nullptr, t1);
    dwgate_kernel<<<dim3(144, 256, 2), 256, 0, stream>>>(t1, dw_w, dw_b, tg);
    conv1x1_kernel<256, false><<<576, 128, 0, stream>>>(tg, pw2_w, pw2_b, 128, ts, nullptr);
    res_set_kernel<<<36864, 256, 0, stream>>>(out, x, ts, beta);

    // ---- stage 2: window attention
    rmsnorm_kernel<<<288, 256, 0, stream>>>(out, at_s, at_b, t0);
    conv1x1_kernel<128, true ><<<576, 128, 0, stream>>>(t0, qkv_w, qkv_b, 384, nullptr, qkvb);
    attn_kernel<<<dim3(2304, 2), 64, 0, stream>>>(qkvb, rpe, attnout);
    conv1x1_kernel<128, false><<<576, 128, 0, stream>>>(attnout, proj_w, proj_b, 128, ts, nullptr);
    res_add_kernel<<<36864, 256, 0, stream>>>(out, ts, alpha);

    // ---- stage 3: gated FFN
    rmsnorm_kernel<<<288, 256, 0, stream>>>(out, ff_s, ff_b, t0);
    conv1x1_kernel<128, true ><<<576, 128, 0, stream>>>(t0, fc1_w, fc1_b, 512, nullptr, t1);
    ffngate_kernel<<<73728, 256, 0, stream>>>(t1, tg);
    conv1x1_kernel<256, false><<<576, 128, 0, stream>>>(tg, fc2_w, fc2_b, 128, ts, nullptr);
    res_add_kernel<<<36864, 256, 0, stream>>>(out, ts, gamma);
}

// Round 2
// 539.858 us; speedup vs baseline: 9.1657x; 9.1657x over previous
//
#include <hip/hip_runtime.h>
#include <hip/hip_bf16.h>
#include <math.h>

#define HW   36864        // 192*192
#define BHW  73728        // 2*HW

typedef float f32x4 __attribute__((ext_vector_type(4)));
typedef short short8 __attribute__((ext_vector_type(8)));

__device__ __forceinline__ unsigned f2bf(float f) {        // fp32 -> bf16 bits, RNE
    unsigned u = __float_as_uint(f);
    return (u + 0x7fffu + ((u >> 16) & 1u)) >> 16;
}
__device__ __forceinline__ float bf2f(unsigned short s) {  // bf16 bits -> fp32
    return __uint_as_float(((unsigned)s) << 16);
}
__device__ __forceinline__ float gelu_erf(float v) {
    return v * 0.5f * (1.0f + erff(v * 0.70710678118654752f));
}

// ---------------------------------------------------------------- weight prep
// fp32 -> bf16 for 6 GEMM weight matrices; dwconv weights transposed to (tap, 512) fp32.
__global__ __launch_bounds__(256)
void wconv_kernel(const float* __restrict__ w1, const float* __restrict__ w2,
                  const float* __restrict__ wq, const float* __restrict__ wp,
                  const float* __restrict__ wf1, const float* __restrict__ wf2,
                  const float* __restrict__ dww,
                  ushort* __restrict__ o1, ushort* __restrict__ o2, ushort* __restrict__ oq,
                  ushort* __restrict__ op, ushort* __restrict__ of1, ushort* __restrict__ of2,
                  float* __restrict__ dwt)
{
    int i = blockIdx.x * 256 + threadIdx.x;
    if      (i <  65536) o1 [i         ] = (ushort)f2bf(w1 [i         ]);
    else if (i <  98304) o2 [i -  65536] = (ushort)f2bf(w2 [i -  65536]);
    else if (i < 147456) oq [i -  98304] = (ushort)f2bf(wq [i -  98304]);
    else if (i < 163840) op [i - 147456] = (ushort)f2bf(wp [i - 147456]);
    else if (i < 229376) of1[i - 163840] = (ushort)f2bf(wf1[i - 163840]);
    else if (i < 262144) of2[i - 229376] = (ushort)f2bf(wf2[i - 229376]);
    else if (i < 266752) {
        int j = i - 262144;            // j = tap*512 + c
        int tap = j >> 9, c = j & 511;
        dwt[j] = dww[c * 9 + tap];
    }
}

// ---------------------------------------------------------------- rmsnorm (NCHW fp32 -> pixel-major bf16)
__global__ __launch_bounds__(256)
void rmsnorm_t_kernel(const float* __restrict__ src, const float* __restrict__ s,
                      const float* __restrict__ bi, __hip_bfloat16* __restrict__ dst)
{
    int P = blockIdx.x * 256 + threadIdx.x;          // pixel id in [0, BHW)
    int b = P / HW, pp = P - b * HW;
    const float* xb = src + (size_t)b * 128 * HW + pp;
    float ss = 0.f;
#pragma unroll 8
    for (int c = 0; c < 128; ++c) { float v = xb[(size_t)c * HW]; ss = fmaf(v, v, ss); }
    float inv = 1.0f / sqrtf(ss * 0.0078125f + 1e-6f);
    unsigned* drow = (unsigned*)(dst + (size_t)P * 128);
#pragma unroll 4
    for (int c = 0; c < 128; c += 2) {
        float v0 = fmaf(s[c]     * xb[(size_t)c * HW],       inv, bi[c]);
        float v1 = fmaf(s[c + 1] * xb[(size_t)(c + 1) * HW], inv, bi[c + 1]);
        drow[c >> 1] = f2bf(v0) | (f2bf(v1) << 16);
    }
}

// ---------------------------------------------------------------- MFMA GEMM
// C[M=BHW, N] = A(M,K) * W(N,K)^T + bias.  A,W bf16 row-major (K contiguous).
// Tile 128x128, BK=32, 4 waves of 64x64 (4x4 16x16x32 mfma).
// MODE 0: store bf16 pixel-major (BHW,N).
// MODE 1: N==128; rdst(NCHW fp32) = rsrc + scale * C   (LDS-transposed coalesced stores).
template<int K, int MODE>
__global__ __launch_bounds__(256)
void gemm_kernel(const __hip_bfloat16* __restrict__ Abf, const __hip_bfloat16* __restrict__ Wbf,
                 const float* __restrict__ bias, int N,
                 __hip_bfloat16* __restrict__ outb,
                 const float* __restrict__ rsrc, float* __restrict__ rdst,
                 const float* __restrict__ scale)
{
    constexpr int SMEM = (MODE == 1) ? 34816 : 16384;
    __shared__ char smem[SMEM];
    short* sA = (short*)smem;           // [128 rows][4 chunks of 8 bf16], chunk-swizzled
    short* sB = sA + 4096;
    float* sEp = (float*)smem;          // MODE1 epilogue: [128 ch][68 px-pad]

    const short* A = (const short*)Abf;
    const short* W = (const short*)Wbf;

    int t = threadIdx.x;
    int lane = t & 63, wv = t >> 6;
    int wm = wv & 1, wn = wv >> 1;
    int m0 = blockIdx.x * 128;
    int n0 = blockIdx.y * 128;
    int q = lane >> 4, r16 = lane & 15;

    f32x4 acc[4][4];
#pragma unroll
    for (int nt = 0; nt < 4; ++nt) {
        float bv = bias[n0 + wn * 64 + nt * 16 + r16];
#pragma unroll
        for (int mt = 0; mt < 4; ++mt) acc[mt][nt] = (f32x4){bv, bv, bv, bv};
    }

    for (int kk = 0; kk < K; kk += 32) {
#pragma unroll
        for (int i = 0; i < 2; ++i) {
            int rbase = wv * 32 + i * 16;
            int row = rbase + (lane >> 2);
            int kc = (lane & 3) ^ ((row >> 1) & 3);
            const short* ga = A + (size_t)(m0 + row) * K + kk + kc * 8;
            const short* gb = W + (size_t)(n0 + row) * K + kk + kc * 8;
            __builtin_amdgcn_global_load_lds((const __attribute__((address_space(1))) void*)ga,
                                             (__attribute__((address_space(3))) void*)(sA + rbase * 32), 16, 0, 0);
            __builtin_amdgcn_global_load_lds((const __attribute__((address_space(1))) void*)gb,
                                             (__attribute__((address_space(3))) void*)(sB + rbase * 32), 16, 0, 0);
        }
        __syncthreads();

        short8 af[4], bf[4];
#pragma unroll
        for (int mt = 0; mt < 4; ++mt) {
            int r = wm * 64 + mt * 16 + r16;
            af[mt] = *(const short8*)(sA + (r * 4 + (q ^ ((r >> 1) & 3))) * 8);
        }
#pragma unroll
        for (int nt = 0; nt < 4; ++nt) {
            int r = wn * 64 + nt * 16 + r16;
            bf[nt] = *(const short8*)(sB + (r * 4 + (q ^ ((r >> 1) & 3))) * 8);
        }
#pragma unroll
        for (int mt = 0; mt < 4; ++mt)
#pragma unroll
            for (int nt = 0; nt < 4; ++nt)
                acc[mt][nt] = __builtin_amdgcn_mfma_f32_16x16x32_bf16(af[mt], bf[nt], acc[mt][nt], 0, 0, 0);
        __syncthreads();
    }

    if constexpr (MODE == 0) {
        ushort* ob = (ushort*)outb;
#pragma unroll
        for (int mt = 0; mt < 4; ++mt) {
            int row0 = m0 + wm * 64 + mt * 16 + q * 4;
#pragma unroll
            for (int nt = 0; nt < 4; ++nt) {
                int col = n0 + wn * 64 + nt * 16 + r16;
#pragma unroll
                for (int rg = 0; rg < 4; ++rg)
                    ob[(size_t)(row0 + rg) * N + col] = (ushort)f2bf(acc[mt][nt][rg]);
            }
        }
    } else {
        float sc = scale[0];
        for (int h = 0; h < 2; ++h) {
            __syncthreads();
            if (wm == h) {
#pragma unroll
                for (int mt = 0; mt < 4; ++mt)
#pragma unroll
                    for (int nt = 0; nt < 4; ++nt) {
                        int c = wn * 64 + nt * 16 + r16;
                        int px = mt * 16 + q * 4;
#pragma unroll
                        for (int rg = 0; rg < 4; ++rg)
                            sEp[c * 68 + px + rg] = acc[mt][nt][rg];
                    }
            }
            __syncthreads();
            int c16 = t >> 4, l16 = t & 15;
            int p0 = m0 + h * 64 + l16 * 4;
            int b = p0 / HW, pp = p0 - b * HW;
#pragma unroll
            for (int i = 0; i < 8; ++i) {
                int c = c16 + i * 16;
                f32x4 v = *(const f32x4*)&sEp[c * 68 + l16 * 4];
                size_t gi = (size_t)(b * 128 + c) * HW + pp;
                f32x4 r = *(const f32x4*)&rsrc[gi];
                f32x4 o = r + sc * v;
                *(f32x4*)&rdst[gi] = o;
            }
        }
    }
}

// ---------------------------------------------------------------- dwconv3x3 + gate (pixel-major bf16)
// t1 (BHW,512): u=cols[0,256), v=cols[256,512).  tg (BHW,256) = u_conv * gelu(v_conv)
__global__ __launch_bounds__(256)
void dwgate_kernel(const __hip_bfloat16* __restrict__ t1, const float* __restrict__ dwt,
                   const float* __restrict__ dwb, __hip_bfloat16* __restrict__ tg)
{
    int t = threadIdx.x;
    int c8 = t & 31, pxl = t >> 5;
    int px = blockIdx.x * 8 + pxl;
    int b = px / HW, pp = px - b * HW;
    int h = pp / 192, w = pp - h * 192;

    float au[8], av[8];
    {
        f32x4 b0 = *(const f32x4*)(dwb + c8 * 8);
        f32x4 b1 = *(const f32x4*)(dwb + c8 * 8 + 4);
        f32x4 b2 = *(const f32x4*)(dwb + 256 + c8 * 8);
        f32x4 b3 = *(const f32x4*)(dwb + 256 + c8 * 8 + 4);
#pragma unroll
        for (int e = 0; e < 4; ++e) { au[e] = b0[e]; au[e + 4] = b1[e]; av[e] = b2[e]; av[e + 4] = b3[e]; }
    }
#pragma unroll
    for (int tap = 0; tap < 9; ++tap) {
        int dy = tap / 3 - 1, dx = tap % 3 - 1;
        int hh = h + dy, w2 = w + dx;
        if (hh < 0 || hh >= 192 || w2 < 0 || w2 >= 192) continue;
        int np = b * HW + hh * 192 + w2;
        const ushort* urow = (const ushort*)t1 + (size_t)np * 512 + c8 * 8;
        short8 u8 = *(const short8*)urow;
        short8 v8 = *(const short8*)(urow + 256);
        f32x4 wu0 = *(const f32x4*)(dwt + tap * 512 + c8 * 8);
        f32x4 wu1 = *(const f32x4*)(dwt + tap * 512 + c8 * 8 + 4);
        f32x4 wv0 = *(const f32x4*)(dwt + tap * 512 + 256 + c8 * 8);
        f32x4 wv1 = *(const f32x4*)(dwt + tap * 512 + 256 + c8 * 8 + 4);
#pragma unroll
        for (int e = 0; e < 4; ++e) {
            au[e]     = fmaf(wu0[e], bf2f((ushort)u8[e]),     au[e]);
            au[e + 4] = fmaf(wu1[e], bf2f((ushort)u8[e + 4]), au[e + 4]);
            av[e]     = fmaf(wv0[e], bf2f((ushort)v8[e]),     av[e]);
            av[e + 4] = fmaf(wv1[e], bf2f((ushort)v8[e + 4]), av[e + 4]);
        }
    }
    short8 o8;
#pragma unroll
    for (int e = 0; e < 8; ++e) o8[e] = (short)(ushort)f2bf(au[e] * gelu_erf(av[e]));
    *(short8*)((ushort*)tg + (size_t)px * 256 + c8 * 8) = o8;
}

// ---------------------------------------------------------------- FFN gate (elementwise)
__global__ __launch_bounds__(256)
void ffngate_kernel(const __hip_bfloat16* __restrict__ t1, __hip_bfloat16* __restrict__ tg)
{
    int t = threadIdx.x;
    int c8 = t & 31, pxl = t >> 5;
    int px = blockIdx.x * 8 + pxl;
    const ushort* urow = (const ushort*)t1 + (size_t)px * 512 + c8 * 8;
    short8 u8 = *(const short8*)urow;
    short8 v8 = *(const short8*)(urow + 256);
    short8 o8;
#pragma unroll
    for (int e = 0; e < 8; ++e) {
        float u = bf2f((ushort)u8[e]), v = bf2f((ushort)v8[e]);
        o8[e] = (short)(ushort)f2bf(u * gelu_erf(v));
    }
    *(short8*)((ushort*)tg + (size_t)px * 256 + c8 * 8) = o8;
}

// ---------------------------------------------------------------- windowed attention
// One wave per (window, head). qkv pixel-major (BHW,384) bf16 -> attno (BHW,128) bf16.
__global__ __launch_bounds__(64)
void attn_kernel(const __hip_bfloat16* __restrict__ qkv, const float* __restrict__ rpe,
                 __hip_bfloat16* __restrict__ attnout)
{
    __shared__ float Ks[32][64];
    __shared__ float Vs[32][64];
    __shared__ float Ss[64][64];
    __shared__ float rpe_s[900];

    int lane = threadIdx.x;
    int head = blockIdx.x & 3;
    int widx = blockIdx.x >> 2;
    int wh = widx / 24, ww = widx % 24;
    int b = blockIdx.y;

    for (int i = lane; i < 900; i += 64) rpe_s[i] = rpe[i];

    int ty = lane >> 3, tx = lane & 7;
    int hr = wh * 8 + ty, wr = ww * 8 + tx;          // rolled-frame coords
    int hs = hr + 4; if (hs >= 192) hs -= 192;       // source/dest coords
    int wsc = wr + 4; if (wsc >= 192) wsc -= 192;
    int pix = hs * 192 + wsc;

    const ushort* base = (const ushort*)qkv + ((size_t)(b * HW + pix)) * 384 + head * 32;
    short8 qv[4], kv[4], vv[4];
#pragma unroll
    for (int i = 0; i < 4; ++i) {
        qv[i] = *(const short8*)(base + i * 8);
        kv[i] = *(const short8*)(base + 128 + i * 8);
        vv[i] = *(const short8*)(base + 256 + i * 8);
    }
    float q[32];
#pragma unroll
    for (int d = 0; d < 32; ++d) q[d] = bf2f((ushort)qv[d >> 3][d & 7]) * 0.17677669529663689f;
#pragma unroll
    for (int d = 0; d < 32; ++d) {
        Ks[d][lane] = bf2f((ushort)kv[d >> 3][d & 7]);
        Vs[d][lane] = bf2f((ushort)vv[d >> 3][d & 7]);
    }
    __syncthreads();

    int rt = ((hr < 184) ? 0 : (hr < 188) ? 1 : 2) * 3 +
             ((wr < 184) ? 0 : (wr < 188) ? 1 : 2);
    bool edge = (wh == 23) || (ww == 23);

    for (int j = 0; j < 64; ++j) {
        float acc = 0.f;
#pragma unroll
        for (int d = 0; d < 32; ++d) acc = fmaf(q[d], Ks[d][j], acc);
        int jy = j >> 3, jx = j & 7;
        acc += rpe_s[((ty - jy + 7) * 15 + (tx - jx + 7)) * 4 + head];
        if (edge) {
            int hj = wh * 8 + jy, wj = ww * 8 + jx;
            int rj = ((hj < 184) ? 0 : (hj < 188) ? 1 : 2) * 3 +
                     ((wj < 184) ? 0 : (wj < 188) ? 1 : 2);
            if (rj != rt) acc = -INFINITY;
        }
        Ss[j][lane] = acc;
    }
    float m = -INFINITY;
    for (int j = 0; j < 64; ++j) m = fmaxf(m, Ss[j][lane]);
    float l = 0.f;
    for (int j = 0; j < 64; ++j) { float e = __expf(Ss[j][lane] - m); Ss[j][lane] = e; l += e; }
    float inv = 1.0f / l;

    float o[32];
#pragma unroll
    for (int d = 0; d < 32; ++d) o[d] = 0.f;
    for (int j = 0; j < 64; ++j) {
        float p = Ss[j][lane];
#pragma unroll
        for (int d = 0; d < 32; ++d) o[d] = fmaf(p, Vs[d][j], o[d]);
    }
    ushort* ob = (ushort*)attnout + ((size_t)(b * HW + pix)) * 128 + head * 32;
#pragma unroll
    for (int g = 0; g < 4; ++g) {
        short8 o8;
#pragma unroll
        for (int e = 0; e < 8; ++e) o8[e] = (short)(ushort)f2bf(o[g * 8 + e] * inv);
        *(short8*)(ob + g * 8) = o8;
    }
}

// ---------------------------------------------------------------- launch
extern "C" void kernel_launch(void* const* d_in, const int* in_sizes, int n_in,
                              void* d_out, int out_size, void* d_ws, size_t ws_size,
                              hipStream_t stream)
{
    const float* x     = (const float*)d_in[0];
    const float* cg_s  = (const float*)d_in[1];
    const float* cg_b  = (const float*)d_in[2];
    const float* pw1_w = (const float*)d_in[3];
    const float* pw1_b = (const float*)d_in[4];
    const float* dw_w  = (const float*)d_in[5];
    const float* dw_b  = (const float*)d_in[6];
    const float* pw2_w = (const float*)d_in[7];
    const float* pw2_b = (const float*)d_in[8];
    const float* beta  = (const float*)d_in[9];
    const float* at_s  = (const float*)d_in[10];
    const float* at_b  = (const float*)d_in[11];
    const float* qkv_w = (const float*)d_in[12];
    const float* qkv_b = (const float*)d_in[13];
    const float* rpe   = (const float*)d_in[14];
    const float* proj_w= (const float*)d_in[15];
    const float* proj_b= (const float*)d_in[16];
    const float* alpha = (const float*)d_in[17];
    const float* ff_s  = (const float*)d_in[18];
    const float* ff_b  = (const float*)d_in[19];
    const float* fc1_w = (const float*)d_in[20];
    const float* fc1_b = (const float*)d_in[21];
    const float* fc2_w = (const float*)d_in[22];
    const float* fc2_b = (const float*)d_in[23];
    const float* gamma = (const float*)d_in[24];
    float* out = (float*)d_out;

    // workspace layout (bytes):
    //   [0, 18.87M)           Xn    bf16 (BHW,128)  rmsnorm out (GEMM A)
    //   [18.87M, 94.37M)      t1    bf16 (BHW,512)  | qkv bf16 (BHW,384) alias
    //   [94.37M, 132.12M)     tg    bf16 (BHW,256)  | attno bf16 (BHW,128) alias
    //   [132.12M, +544K)      bf16 weights + dwt
    char* ws = (char*)d_ws;
    __hip_bfloat16* Xn    = (__hip_bfloat16*)ws;
    __hip_bfloat16* t1    = (__hip_bfloat16*)(ws + 18874368);
    __hip_bfloat16* qkvb  = t1;
    __hip_bfloat16* tg    = (__hip_bfloat16*)(ws + 94371840);
    __hip_bfloat16* attno = tg;
    char* wsw = ws + 132120576;
    ushort* w1b  = (ushort*)(wsw);             // 512*128 bf16  = 131072 B
    ushort* w2b  = (ushort*)(wsw + 131072);    // 128*256       =  65536 B
    ushort* wqb  = (ushort*)(wsw + 196608);    // 384*128       =  98304 B
    ushort* wpb  = (ushort*)(wsw + 294912);    // 128*128       =  32768 B
    ushort* wf1b = (ushort*)(wsw + 327680);    // 512*128       = 131072 B
    ushort* wf2b = (ushort*)(wsw + 458752);    // 128*256       =  65536 B
    float*  dwt  = (float*) (wsw + 524288);    // 9*512 fp32    =  18432 B

    wconv_kernel<<<1042, 256, 0, stream>>>(pw1_w, pw2_w, qkv_w, proj_w, fc1_w, fc2_w, dw_w,
                                           w1b, w2b, wqb, wpb, wf1b, wf2b, dwt);

    // ---- stage 1: conv_gated_block
    rmsnorm_t_kernel<<<288, 256, 0, stream>>>(x, cg_s, cg_b, Xn);
    gemm_kernel<128, 0><<<dim3(576, 4), 256, 0, stream>>>(Xn, (__hip_bfloat16*)w1b, pw1_b, 512, t1, nullptr, nullptr, nullptr);
    dwgate_kernel<<<9216, 256, 0, stream>>>(t1, dwt, dw_b, tg);
    gemm_kernel<256, 1><<<dim3(576, 1), 256, 0, stream>>>(tg, (__hip_bfloat16*)w2b, pw2_b, 128, nullptr, x, out, beta);

    // ---- stage 2: window attention
    rmsnorm_t_kernel<<<288, 256, 0, stream>>>(out, at_s, at_b, Xn);
    gemm_kernel<128, 0><<<dim3(576, 3), 256, 0, stream>>>(Xn, (__hip_bfloat16*)wqb, qkv_b, 384, qkvb, nullptr, nullptr, nullptr);
    attn_kernel<<<dim3(2304, 2), 64, 0, stream>>>(qkvb, rpe, attno);
    gemm_kernel<128, 1><<<dim3(576, 1), 256, 0, stream>>>(attno, (__hip_bfloat16*)wpb, proj_b, 128, nullptr, out, out, alpha);

    // ---- stage 3: gated FFN
    rmsnorm_t_kernel<<<288, 256, 0, stream>>>(out, ff_s, ff_b, Xn);
    gemm_kernel<128, 0><<<dim3(576, 4), 256, 0, stream>>>(Xn, (__hip_bfloat16*)wf1b, fc1_b, 512, t1, nullptr, nullptr, nullptr);
    ffngate_kernel<<<9216, 256, 0, stream>>>(t1, tg);
    gemm_kernel<256, 1><<<dim3(576, 1), 256, 0, stream>>>(tg, (__hip_bfloat16*)wf2b, fc2_b, 128, nullptr, out, out, gamma);
}

// Round 4
// 454.539 us; speedup vs baseline: 10.8862x; 1.1877x over previous
//
#include <hip/hip_runtime.h>
#include <hip/hip_bf16.h>
#include <math.h>

#define HW   36864        // 192*192
#define BHW  73728        // 2*HW

typedef float f32x4 __attribute__((ext_vector_type(4)));
typedef short short8 __attribute__((ext_vector_type(8)));

__device__ __forceinline__ unsigned f2bf(float f) {        // fp32 -> bf16 bits, RNE
    unsigned u = __float_as_uint(f);
    return (u + 0x7fffu + ((u >> 16) & 1u)) >> 16;
}
__device__ __forceinline__ float bf2f(unsigned short s) {  // bf16 bits -> fp32
    return __uint_as_float(((unsigned)s) << 16);
}
__device__ __forceinline__ float gelu_erf(float v) {
    return v * 0.5f * (1.0f + erff(v * 0.70710678118654752f));
}

// ---------------------------------------------------------------- weight prep
__global__ __launch_bounds__(256)
void wconv_kernel(const float* __restrict__ w1, const float* __restrict__ w2,
                  const float* __restrict__ wq, const float* __restrict__ wp,
                  const float* __restrict__ wf1, const float* __restrict__ wf2,
                  const float* __restrict__ dww,
                  ushort* __restrict__ o1, ushort* __restrict__ o2, ushort* __restrict__ oq,
                  ushort* __restrict__ op, ushort* __restrict__ of1, ushort* __restrict__ of2,
                  float* __restrict__ dwt)
{
    int i = blockIdx.x * 256 + threadIdx.x;
    if      (i <  65536) o1 [i         ] = (ushort)f2bf(w1 [i         ]);
    else if (i <  98304) o2 [i -  65536] = (ushort)f2bf(w2 [i -  65536]);
    else if (i < 147456) oq [i -  98304] = (ushort)f2bf(wq [i -  98304]);
    else if (i < 163840) op [i - 147456] = (ushort)f2bf(wp [i - 147456]);
    else if (i < 229376) of1[i - 163840] = (ushort)f2bf(wf1[i - 163840]);
    else if (i < 262144) of2[i - 229376] = (ushort)f2bf(wf2[i - 229376]);
    else if (i < 266752) {
        int j = i - 262144;            // j = tap*512 + c
        int tap = j >> 9, c = j & 511;
        dwt[j] = dww[c * 9 + tap];
    }
}

// ---------------------------------------------------------------- rmsnorm (NCHW fp32 -> pixel-major bf16)
__global__ __launch_bounds__(256)
void rmsnorm_t_kernel(const float* __restrict__ src, const float* __restrict__ s,
                      const float* __restrict__ bi, __hip_bfloat16* __restrict__ dst)
{
    int P = blockIdx.x * 256 + threadIdx.x;          // pixel id in [0, BHW)
    int b = P / HW, pp = P - b * HW;
    const float* xb = src + (size_t)b * 128 * HW + pp;
    float ss = 0.f;
#pragma unroll 8
    for (int c = 0; c < 128; ++c) { float v = xb[(size_t)c * HW]; ss = fmaf(v, v, ss); }
    float inv = 1.0f / sqrtf(ss * 0.0078125f + 1e-6f);
    unsigned* drow = (unsigned*)(dst + (size_t)P * 128);
#pragma unroll 4
    for (int c = 0; c < 128; c += 2) {
        float v0 = fmaf(s[c]     * xb[(size_t)c * HW],       inv, bi[c]);
        float v1 = fmaf(s[c + 1] * xb[(size_t)(c + 1) * HW], inv, bi[c + 1]);
        drow[c >> 1] = f2bf(v0) | (f2bf(v1) << 16);
    }
}

// ---------------------------------------------------------------- MFMA GEMM
template<int K, int MODE>
__global__ __launch_bounds__(256)
void gemm_kernel(const __hip_bfloat16* __restrict__ Abf, const __hip_bfloat16* __restrict__ Wbf,
                 const float* __restrict__ bias, int N,
                 __hip_bfloat16* __restrict__ outb,
                 const float* __restrict__ rsrc, float* __restrict__ rdst,
                 const float* __restrict__ scale)
{
    constexpr int SMEM = (MODE == 1) ? 34816 : 16384;
    __shared__ char smem[SMEM];
    short* sA = (short*)smem;
    short* sB = sA + 4096;
    float* sEp = (float*)smem;

    const short* A = (const short*)Abf;
    const short* W = (const short*)Wbf;

    int t = threadIdx.x;
    int lane = t & 63, wv = t >> 6;
    int wm = wv & 1, wn = wv >> 1;
    int m0 = blockIdx.x * 128;
    int n0 = blockIdx.y * 128;
    int q = lane >> 4, r16 = lane & 15;

    f32x4 acc[4][4];
#pragma unroll
    for (int nt = 0; nt < 4; ++nt) {
        float bv = bias[n0 + wn * 64 + nt * 16 + r16];
#pragma unroll
        for (int mt = 0; mt < 4; ++mt) acc[mt][nt] = (f32x4){bv, bv, bv, bv};
    }

    for (int kk = 0; kk < K; kk += 32) {
#pragma unroll
        for (int i = 0; i < 2; ++i) {
            int rbase = wv * 32 + i * 16;
            int row = rbase + (lane >> 2);
            int kc = (lane & 3) ^ ((row >> 1) & 3);
            const short* ga = A + (size_t)(m0 + row) * K + kk + kc * 8;
            const short* gb = W + (size_t)(n0 + row) * K + kk + kc * 8;
            __builtin_amdgcn_global_load_lds((const __attribute__((address_space(1))) void*)ga,
                                             (__attribute__((address_space(3))) void*)(sA + rbase * 32), 16, 0, 0);
            __builtin_amdgcn_global_load_lds((const __attribute__((address_space(1))) void*)gb,
                                             (__attribute__((address_space(3))) void*)(sB + rbase * 32), 16, 0, 0);
        }
        __syncthreads();

        short8 af[4], bf[4];
#pragma unroll
        for (int mt = 0; mt < 4; ++mt) {
            int r = wm * 64 + mt * 16 + r16;
            af[mt] = *(const short8*)(sA + (r * 4 + (q ^ ((r >> 1) & 3))) * 8);
        }
#pragma unroll
        for (int nt = 0; nt < 4; ++nt) {
            int r = wn * 64 + nt * 16 + r16;
            bf[nt] = *(const short8*)(sB + (r * 4 + (q ^ ((r >> 1) & 3))) * 8);
        }
#pragma unroll
        for (int mt = 0; mt < 4; ++mt)
#pragma unroll
            for (int nt = 0; nt < 4; ++nt)
                acc[mt][nt] = __builtin_amdgcn_mfma_f32_16x16x32_bf16(af[mt], bf[nt], acc[mt][nt], 0, 0, 0);
        __syncthreads();
    }

    if constexpr (MODE == 0) {
        ushort* ob = (ushort*)outb;
#pragma unroll
        for (int mt = 0; mt < 4; ++mt) {
            int row0 = m0 + wm * 64 + mt * 16 + q * 4;
#pragma unroll
            for (int nt = 0; nt < 4; ++nt) {
                int col = n0 + wn * 64 + nt * 16 + r16;
#pragma unroll
                for (int rg = 0; rg < 4; ++rg)
                    ob[(size_t)(row0 + rg) * N + col] = (ushort)f2bf(acc[mt][nt][rg]);
            }
        }
    } else {
        float sc = scale[0];
        for (int h = 0; h < 2; ++h) {
            __syncthreads();
            if (wm == h) {
#pragma unroll
                for (int mt = 0; mt < 4; ++mt)
#pragma unroll
                    for (int nt = 0; nt < 4; ++nt) {
                        int c = wn * 64 + nt * 16 + r16;
                        int px = mt * 16 + q * 4;
#pragma unroll
                        for (int rg = 0; rg < 4; ++rg)
                            sEp[c * 68 + px + rg] = acc[mt][nt][rg];
                    }
            }
            __syncthreads();
            int c16 = t >> 4, l16 = t & 15;
            int p0 = m0 + h * 64 + l16 * 4;
            int b = p0 / HW, pp = p0 - b * HW;
#pragma unroll
            for (int i = 0; i < 8; ++i) {
                int c = c16 + i * 16;
                f32x4 v = *(const f32x4*)&sEp[c * 68 + l16 * 4];
                size_t gi = (size_t)(b * 128 + c) * HW + pp;
                f32x4 r = *(const f32x4*)&rsrc[gi];
                f32x4 o = r + sc * v;
                *(f32x4*)&rdst[gi] = o;
            }
        }
    }
}

// ---------------------------------------------------------------- dwconv3x3 + gate (pixel-major bf16)
__global__ __launch_bounds__(256)
void dwgate_kernel(const __hip_bfloat16* __restrict__ t1, const float* __restrict__ dwt,
                   const float* __restrict__ dwb, __hip_bfloat16* __restrict__ tg)
{
    int t = threadIdx.x;
    int c8 = t & 31, pxl = t >> 5;
    int px = blockIdx.x * 8 + pxl;
    int b = px / HW, pp = px - b * HW;
    int h = pp / 192, w = pp - h * 192;

    float au[8], av[8];
    {
        f32x4 b0 = *(const f32x4*)(dwb + c8 * 8);
        f32x4 b1 = *(const f32x4*)(dwb + c8 * 8 + 4);
        f32x4 b2 = *(const f32x4*)(dwb + 256 + c8 * 8);
        f32x4 b3 = *(const f32x4*)(dwb + 256 + c8 * 8 + 4);
#pragma unroll
        for (int e = 0; e < 4; ++e) { au[e] = b0[e]; au[e + 4] = b1[e]; av[e] = b2[e]; av[e + 4] = b3[e]; }
    }
#pragma unroll
    for (int tap = 0; tap < 9; ++tap) {
        int dy = tap / 3 - 1, dx = tap % 3 - 1;
        int hh = h + dy, w2 = w + dx;
        if (hh < 0 || hh >= 192 || w2 < 0 || w2 >= 192) continue;
        int np = b * HW + hh * 192 + w2;
        const ushort* urow = (const ushort*)t1 + (size_t)np * 512 + c8 * 8;
        short8 u8 = *(const short8*)urow;
        short8 v8 = *(const short8*)(urow + 256);
        f32x4 wu0 = *(const f32x4*)(dwt + tap * 512 + c8 * 8);
        f32x4 wu1 = *(const f32x4*)(dwt + tap * 512 + c8 * 8 + 4);
        f32x4 wv0 = *(const f32x4*)(dwt + tap * 512 + 256 + c8 * 8);
        f32x4 wv1 = *(const f32x4*)(dwt + tap * 512 + 256 + c8 * 8 + 4);
#pragma unroll
        for (int e = 0; e < 4; ++e) {
            au[e]     = fmaf(wu0[e], bf2f((ushort)u8[e]),     au[e]);
            au[e + 4] = fmaf(wu1[e], bf2f((ushort)u8[e + 4]), au[e + 4]);
            av[e]     = fmaf(wv0[e], bf2f((ushort)v8[e]),     av[e]);
            av[e + 4] = fmaf(wv1[e], bf2f((ushort)v8[e + 4]), av[e + 4]);
        }
    }
    short8 o8;
#pragma unroll
    for (int e = 0; e < 8; ++e) o8[e] = (short)(ushort)f2bf(au[e] * gelu_erf(av[e]));
    *(short8*)((ushort*)tg + (size_t)px * 256 + c8 * 8) = o8;
}

// ---------------------------------------------------------------- FFN gate (elementwise)
__global__ __launch_bounds__(256)
void ffngate_kernel(const __hip_bfloat16* __restrict__ t1, __hip_bfloat16* __restrict__ tg)
{
    int t = threadIdx.x;
    int c8 = t & 31, pxl = t >> 5;
    int px = blockIdx.x * 8 + pxl;
    const ushort* urow = (const ushort*)t1 + (size_t)px * 512 + c8 * 8;
    short8 u8 = *(const short8*)urow;
    short8 v8 = *(const short8*)(urow + 256);
    short8 o8;
#pragma unroll
    for (int e = 0; e < 8; ++e) {
        float u = bf2f((ushort)u8[e]), v = bf2f((ushort)v8[e]);
        o8[e] = (short)(ushort)f2bf(u * gelu_erf(v));
    }
    *(short8*)((ushort*)tg + (size_t)px * 256 + c8 * 8) = o8;
}

// ---------------------------------------------------------------- windowed attention (MFMA)
// One 256-thread block per (window, batch); wave = head.
// NOTE: P/VT/Of LDS round-trips mix pointer types (ushort writes / uint reads,
// float writes after uint reads). TBAA says those don't alias, so the compiler
// may reorder ds ops across the round-trip -> garbage (NaN) reads. Every LDS
// write->read (and read->overwrite) transition is therefore fenced with
// __syncthreads(), which is a compiler memory barrier. (Round-3 NaN root cause.)
__device__ __forceinline__ int wpix(int wh, int ww, int m) {
    int ty = m >> 3, tx = m & 7;
    int hs = wh * 8 + ty + 4; if (hs >= 192) hs -= 192;
    int wsc = ww * 8 + tx + 4; if (wsc >= 192) wsc -= 192;
    return hs * 192 + wsc;
}
__device__ __forceinline__ int wreg(int wh, int ww, int m) {   // shift-mask region id
    int hr = wh * 8 + (m >> 3), wr = ww * 8 + (m & 7);
    return ((hr < 184) ? 0 : (hr < 188) ? 1 : 2) * 3 +
           ((wr < 184) ? 0 : (wr < 188) ? 1 : 2);
}

__global__ __launch_bounds__(256)
void attn_kernel(const __hip_bfloat16* __restrict__ qkv, const float* __restrict__ rpe,
                 __hip_bfloat16* __restrict__ attnout)
{
    // LDS per head: P 64 rows x 132B (bf16) = 8448B, VT 32 rows x 132B = 4224B.
    // 132B = odd-dword row stride -> strided accesses <=2-way bank aliased (free).
    __shared__ char smem[54288];
    int t = threadIdx.x;
    int lane = t & 63, head = t >> 6;
    int wh = blockIdx.x / 24, ww = blockIdx.x % 24;
    int b = blockIdx.y;
    int q = lane >> 4, r16 = lane & 15;

    float* rpe_s = (float*)(smem + 50688);
    for (int i = t; i < 900; i += 256) rpe_s[i] = rpe[i];

    char* Pbuf  = smem + head * 12672;
    char* VTbuf = Pbuf + 8448;
    const ushort* qkvu = (const ushort*)qkv;

    // ---- Q/K fragments straight from global (k = head-dim, contiguous)
    short8 aq[4], bk[4];
#pragma unroll
    for (int mt = 0; mt < 4; ++mt) {
        int pix = wpix(wh, ww, mt * 16 + r16);
        const ushort* rowp = qkvu + (size_t)(b * HW + pix) * 384 + head * 32 + q * 8;
        aq[mt] = *(const short8*)rowp;
        bk[mt] = *(const short8*)(rowp + 128);
    }
    // ---- V transpose into LDS (lane = pixel)
    {
        int pix = wpix(wh, ww, lane);
        const ushort* vp = qkvu + (size_t)(b * HW + pix) * 384 + 256 + head * 32;
        ushort* vt = (ushort*)VTbuf;           // VT[d][j]: row stride 66 ushorts
#pragma unroll
        for (int g = 0; g < 4; ++g) {
            short8 v8 = *(const short8*)(vp + g * 8);
#pragma unroll
            for (int e = 0; e < 8; ++e) vt[(g * 8 + e) * 66 + lane] = (ushort)v8[e];
        }
    }
    __syncthreads();   // rpe_s + VT writes ordered before reads

    // ---- S = Q*K^T (16 MFMAs)
    f32x4 s[4][4];
#pragma unroll
    for (int mt = 0; mt < 4; ++mt)
#pragma unroll
        for (int nt = 0; nt < 4; ++nt) s[mt][nt] = (f32x4){0.f, 0.f, 0.f, 0.f};
#pragma unroll
    for (int mt = 0; mt < 4; ++mt)
#pragma unroll
        for (int nt = 0; nt < 4; ++nt)
            s[mt][nt] = __builtin_amdgcn_mfma_f32_16x16x32_bf16(aq[mt], bk[nt], s[mt][nt], 0, 0, 0);

    // ---- logits + row softmax on C-layout fragments
    bool edge = (wh == 23) || (ww == 23);
    int tyj[4], txj[4], rgj[4];
#pragma unroll
    for (int nt = 0; nt < 4; ++nt) {
        int j = nt * 16 + r16;
        tyj[nt] = j >> 3; txj[nt] = j & 7;
        rgj[nt] = wreg(wh, ww, j);
    }
    float rinv[4][4];
#pragma unroll
    for (int mt = 0; mt < 4; ++mt) {
#pragma unroll
        for (int rg = 0; rg < 4; ++rg) {
            int i = mt * 16 + q * 4 + rg;
            int tyi = i >> 3, txi = i & 7;
            int rgi = edge ? wreg(wh, ww, i) : 0;
            float mx = -INFINITY;
#pragma unroll
            for (int nt = 0; nt < 4; ++nt) {
                float v = s[mt][nt][rg] * 0.17677669529663689f
                        + rpe_s[((tyi - tyj[nt] + 7) * 15 + (txi - txj[nt] + 7)) * 4 + head];
                if (edge && rgi != rgj[nt]) v = -INFINITY;
                s[mt][nt][rg] = v;
                mx = fmaxf(mx, v);
            }
            mx = fmaxf(mx, __shfl_xor(mx, 1));
            mx = fmaxf(mx, __shfl_xor(mx, 2));
            mx = fmaxf(mx, __shfl_xor(mx, 4));
            mx = fmaxf(mx, __shfl_xor(mx, 8));
            float sum = 0.f;
#pragma unroll
            for (int nt = 0; nt < 4; ++nt) {
                float e = __expf(s[mt][nt][rg] - mx);
                s[mt][nt][rg] = e;
                sum += e;
            }
            sum += __shfl_xor(sum, 1);
            sum += __shfl_xor(sum, 2);
            sum += __shfl_xor(sum, 4);
            sum += __shfl_xor(sum, 8);
            rinv[mt][rg] = 1.0f / sum;
        }
    }

    // ---- P -> LDS (C-layout write, bf16)
    ushort* Pu = (ushort*)Pbuf;                 // row stride 66 ushorts
#pragma unroll
    for (int mt = 0; mt < 4; ++mt)
#pragma unroll
        for (int rg = 0; rg < 4; ++rg) {
            int i = mt * 16 + q * 4 + rg;
#pragma unroll
            for (int nt = 0; nt < 4; ++nt)
                Pu[i * 66 + nt * 16 + r16] = (ushort)f2bf(s[mt][nt][rg]);
        }
    __syncthreads();   // fence: P ushort-writes before uint-reads (TBAA)

    // ---- O = P*V (16 MFMAs), P read in A-layout, VT read in B-layout
    f32x4 o[4][2];
#pragma unroll
    for (int mt = 0; mt < 4; ++mt) { o[mt][0] = (f32x4){0,0,0,0}; o[mt][1] = (f32x4){0,0,0,0}; }
    const uint* Pw = (const uint*)Pbuf;         // dword units, row stride 33
    const uint* Vw = (const uint*)VTbuf;
#pragma unroll
    for (int ks = 0; ks < 2; ++ks) {
        short8 ap[4];
#pragma unroll
        for (int mt = 0; mt < 4; ++mt) {
            int base = (mt * 16 + r16) * 33 + ks * 16 + q * 4;
            uint d0 = Pw[base], d1 = Pw[base + 1], d2 = Pw[base + 2], d3 = Pw[base + 3];
            union { uint u[4]; short8 s8; } cv; cv.u[0] = d0; cv.u[1] = d1; cv.u[2] = d2; cv.u[3] = d3;
            ap[mt] = cv.s8;
        }
        short8 bv[2];
#pragma unroll
        for (int nt = 0; nt < 2; ++nt) {
            int base = (nt * 16 + r16) * 33 + ks * 16 + q * 4;
            uint d0 = Vw[base], d1 = Vw[base + 1], d2 = Vw[base + 2], d3 = Vw[base + 3];
            union { uint u[4]; short8 s8; } cv; cv.u[0] = d0; cv.u[1] = d1; cv.u[2] = d2; cv.u[3] = d3;
            bv[nt] = cv.s8;
        }
#pragma unroll
        for (int mt = 0; mt < 4; ++mt)
#pragma unroll
            for (int nt = 0; nt < 2; ++nt)
                o[mt][nt] = __builtin_amdgcn_mfma_f32_16x16x32_bf16(ap[mt], bv[nt], o[mt][nt], 0, 0, 0);
    }
    __syncthreads();   // fence: P uint-reads complete before Of float-overwrite (TBAA WAR)

    // ---- epilogue: transpose O through LDS (reuse Pbuf), coalesced bf16 store
    float* Of = (float*)Pbuf;                   // row stride 33 dwords
#pragma unroll
    for (int mt = 0; mt < 4; ++mt)
#pragma unroll
        for (int rg = 0; rg < 4; ++rg) {
            int i = mt * 16 + q * 4 + rg;
            float sc = rinv[mt][rg];
            Of[i * 33 + r16]      = o[mt][0][rg] * sc;
            Of[i * 33 + 16 + r16] = o[mt][1][rg] * sc;
        }
    __syncthreads();   // fence: Of writes before cross-lane reads
    {
        int pix = wpix(wh, ww, lane);
        ushort* ob = (ushort*)attnout + (size_t)(b * HW + pix) * 128 + head * 32;
#pragma unroll
        for (int g = 0; g < 4; ++g) {
            short8 o8;
#pragma unroll
            for (int e = 0; e < 8; ++e) o8[e] = (short)(ushort)f2bf(Of[lane * 33 + g * 8 + e]);
            *(short8*)(ob + g * 8) = o8;
        }
    }
}

// ---------------------------------------------------------------- launch
extern "C" void kernel_launch(void* const* d_in, const int* in_sizes, int n_in,
                              void* d_out, int out_size, void* d_ws, size_t ws_size,
                              hipStream_t stream)
{
    const float* x     = (const float*)d_in[0];
    const float* cg_s  = (const float*)d_in[1];
    const float* cg_b  = (const float*)d_in[2];
    const float* pw1_w = (const float*)d_in[3];
    const float* pw1_b = (const float*)d_in[4];
    const float* dw_w  = (const float*)d_in[5];
    const float* dw_b  = (const float*)d_in[6];
    const float* pw2_w = (const float*)d_in[7];
    const float* pw2_b = (const float*)d_in[8];
    const float* beta  = (const float*)d_in[9];
    const float* at_s  = (const float*)d_in[10];
    const float* at_b  = (const float*)d_in[11];
    const float* qkv_w = (const float*)d_in[12];
    const float* qkv_b = (const float*)d_in[13];
    const float* rpe   = (const float*)d_in[14];
    const float* proj_w= (const float*)d_in[15];
    const float* proj_b= (const float*)d_in[16];
    const float* alpha = (const float*)d_in[17];
    const float* ff_s  = (const float*)d_in[18];
    const float* ff_b  = (const float*)d_in[19];
    const float* fc1_w = (const float*)d_in[20];
    const float* fc1_b = (const float*)d_in[21];
    const float* fc2_w = (const float*)d_in[22];
    const float* fc2_b = (const float*)d_in[23];
    const float* gamma = (const float*)d_in[24];
    float* out = (float*)d_out;

    char* ws = (char*)d_ws;
    __hip_bfloat16* Xn    = (__hip_bfloat16*)ws;
    __hip_bfloat16* t1    = (__hip_bfloat16*)(ws + 18874368);
    __hip_bfloat16* qkvb  = t1;
    __hip_bfloat16* tg    = (__hip_bfloat16*)(ws + 94371840);
    __hip_bfloat16* attno = tg;
    char* wsw = ws + 132120576;
    ushort* w1b  = (ushort*)(wsw);
    ushort* w2b  = (ushort*)(wsw + 131072);
    ushort* wqb  = (ushort*)(wsw + 196608);
    ushort* wpb  = (ushort*)(wsw + 294912);
    ushort* wf1b = (ushort*)(wsw + 327680);
    ushort* wf2b = (ushort*)(wsw + 458752);
    float*  dwt  = (float*) (wsw + 524288);

    wconv_kernel<<<1042, 256, 0, stream>>>(pw1_w, pw2_w, qkv_w, proj_w, fc1_w, fc2_w, dw_w,
                                           w1b, w2b, wqb, wpb, wf1b, wf2b, dwt);

    // ---- stage 1: conv_gated_block
    rmsnorm_t_kernel<<<288, 256, 0, stream>>>(x, cg_s, cg_b, Xn);
    gemm_kernel<128, 0><<<dim3(576, 4), 256, 0, stream>>>(Xn, (__hip_bfloat16*)w1b, pw1_b, 512, t1, nullptr, nullptr, nullptr);
    dwgate_kernel<<<9216, 256, 0, stream>>>(t1, dwt, dw_b, tg);
    gemm_kernel<256, 1><<<dim3(576, 1), 256, 0, stream>>>(tg, (__hip_bfloat16*)w2b, pw2_b, 128, nullptr, x, out, beta);

    // ---- stage 2: window attention
    rmsnorm_t_kernel<<<288, 256, 0, stream>>>(out, at_s, at_b, Xn);
    gemm_kernel<128, 0><<<dim3(576, 3), 256, 0, stream>>>(Xn, (__hip_bfloat16*)wqb, qkv_b, 384, qkvb, nullptr, nullptr, nullptr);
    attn_kernel<<<dim3(576, 2), 256, 0, stream>>>(qkvb, rpe, attno);
    gemm_kernel<128, 1><<<dim3(576, 1), 256, 0, stream>>>(attno, (__hip_bfloat16*)wpb, proj_b, 128, nullptr, out, out, alpha);

    // ---- stage 3: gated FFN
    rmsnorm_t_kernel<<<288, 256, 0, stream>>>(out, ff_s, ff_b, Xn);
    gemm_kernel<128, 0><<<dim3(576, 4), 256, 0, stream>>>(Xn, (__hip_bfloat16*)wf1b, fc1_b, 512, t1, nullptr, nullptr, nullptr);
    ffngate_kernel<<<9216, 256, 0, stream>>>(t1, tg);
    gemm_kernel<256, 1><<<dim3(576, 1), 256, 0, stream>>>(tg, (__hip_bfloat16*)wf2b, fc2_b, 128, nullptr, out, out, gamma);
}